// Round 1
// baseline (229.432 us; speedup 1.0000x reference)
//
#include <hip/hip_runtime.h>

typedef _Float16 f16;
typedef _Float16 f16x4 __attribute__((ext_vector_type(4)));
typedef _Float16 f16x8 __attribute__((ext_vector_type(8)));
typedef float    f32x4 __attribute__((ext_vector_type(4)));

#define NEG_INF (-__builtin_inff())
static constexpr float L2E = 1.44269504088896340736f;

static __device__ __forceinline__ f32x4 mfma16(f16x8 a, f16x8 b, f32x4 c) {
    return __builtin_amdgcn_mfma_f32_16x16x32_f16(a, b, c, 0, 0, 0);
}

// ---------------------------------------------------------------------------
// Kernel 0: transpose W [512][64] f32 -> WT [64][512] f16 (per tensor)
// ---------------------------------------------------------------------------
__global__ void ah_wt_prep(const float* __restrict__ Wq,
                           const float* __restrict__ Wk,
                           const float* __restrict__ Wv,
                           f16* __restrict__ WT) {
    const float* W = (blockIdx.x == 0) ? Wq : (blockIdx.x == 1) ? Wk : Wv;
    f16* o = WT + (size_t)blockIdx.x * (64 * 512);
    for (int i = threadIdx.x; i < 64 * 512; i += blockDim.x) {
        int col = i >> 9, e = i & 511;
        o[i] = (f16)W[e * 64 + col];
    }
}

// ---------------------------------------------------------------------------
// Kernel 1: projection  P = X @ W + b   (X fp32 [32768][512], out f16)
// grid (256 row-tiles, 3 tensors), block 256 (4 waves x 32 rows)
// tensor 0 -> qp row-major, 1 -> kp row-major, 2 -> vpT transposed [b][64][4096]
// ---------------------------------------------------------------------------
__global__ __launch_bounds__(256) void ah_proj(
    const float* __restrict__ Xq, const float* __restrict__ Xk, const float* __restrict__ Xv,
    const float* __restrict__ bq, const float* __restrict__ bk, const float* __restrict__ bv,
    const f16* __restrict__ WT,
    f16* __restrict__ qp, f16* __restrict__ kp, f16* __restrict__ vpT) {

    const int tens = blockIdx.y;
    const float* X    = (tens == 0) ? Xq : (tens == 1) ? Xk : Xv;
    const float* bias = (tens == 0) ? bq : (tens == 1) ? bk : bv;
    const f16* wt = WT + (size_t)tens * (64 * 512);

    const int lane = threadIdx.x & 63;
    const int wave = threadIdx.x >> 6;
    const int l15 = lane & 15, g = lane >> 4;
    const int row0 = blockIdx.x * 128;   // global row base of this block
    const int wrow = wave * 32;          // row base within block

    f32x4 acc[2][4];
#pragma unroll
    for (int a = 0; a < 2; ++a)
#pragma unroll
        for (int b = 0; b < 4; ++b) acc[a][b] = (f32x4){0.f, 0.f, 0.f, 0.f};

#pragma unroll 4
    for (int ec = 0; ec < 16; ++ec) {            // K = 512 in chunks of 32
        f16x8 af[2];
#pragma unroll
        for (int rf = 0; rf < 2; ++rf) {
            const float* px = X + (size_t)(row0 + wrow + rf * 16 + l15) * 512 + ec * 32 + g * 8;
            float4 v0 = *(const float4*)px;
            float4 v1 = *(const float4*)(px + 4);
            f16x8 a;
            a[0] = (f16)v0.x; a[1] = (f16)v0.y; a[2] = (f16)v0.z; a[3] = (f16)v0.w;
            a[4] = (f16)v1.x; a[5] = (f16)v1.y; a[6] = (f16)v1.z; a[7] = (f16)v1.w;
            af[rf] = a;
        }
#pragma unroll
        for (int cf = 0; cf < 4; ++cf) {
            f16x8 bfr = *(const f16x8*)(wt + (size_t)(cf * 16 + l15) * 512 + ec * 32 + g * 8);
#pragma unroll
            for (int rf = 0; rf < 2; ++rf)
                acc[rf][cf] = mfma16(af[rf], bfr, acc[rf][cf]);
        }
    }

    // epilogue: bias + f16, stage in LDS [128][68]
    __shared__ __align__(16) f16 lds[128 * 68];
#pragma unroll
    for (int rf = 0; rf < 2; ++rf)
#pragma unroll
        for (int cf = 0; cf < 4; ++cf) {
            float b = bias[cf * 16 + l15];
#pragma unroll
            for (int r = 0; r < 4; ++r) {
                int rr = wrow + rf * 16 + g * 4 + r;   // C layout: row=(l>>4)*4+r
                lds[rr * 68 + cf * 16 + l15] = (f16)(acc[rf][cf][r] + b);
            }
        }
    __syncthreads();

    if (tens < 2) {
        f16* o = ((tens == 0) ? qp : kp) + (size_t)row0 * 64;
        for (int c = threadIdx.x; c < 128 * 16; c += 256) {  // 8B chunks
            int r = c >> 4, ch = c & 15;
            *(f16x4*)(o + r * 64 + ch * 4) = *(const f16x4*)(&lds[r * 68 + ch * 4]);
        }
    } else {
        int b = row0 >> 12, n0 = row0 & 4095;
        f16* o = vpT + (size_t)b * 64 * 4096 + n0;
        for (int c = threadIdx.x; c < 64 * 32; c += 256) {   // 64 dvals x 32 chunks of 4 n
            int d = c >> 5, nch = c & 31;
            f16x4 v;
#pragma unroll
            for (int j = 0; j < 4; ++j) v[j] = lds[(nch * 4 + j) * 68 + d];
            *(f16x4*)(o + (size_t)d * 4096 + nch * 4) = v;
        }
    }
}

// ---------------------------------------------------------------------------
// Kernel 2: fused flash attention.
// grid 256: batch = id&7 (XCD-pinned), qtile = id>>3 (128 q-rows).
// block 512 = 8 waves: qgroup = w>>1 (32 q each), keysplit s = w&1.
// Swapped QK^T: S^T[key][q] = mfma(A=kp, B=qp). Online softmax in exp2 domain.
// PV: O^T[dval][q] = mfma(A=vpT, B=P^T) with P via wave-private LDS.
// ---------------------------------------------------------------------------
__global__ __launch_bounds__(512, 2) void ah_attn(
    const f16* __restrict__ qp, const f16* __restrict__ kp, const f16* __restrict__ vpT,
    const int* __restrict__ maskp, float* __restrict__ out) {

    const int id = blockIdx.x;
    const int batch = id & 7, qtile = id >> 3;
    const int lane = threadIdx.x & 63, wave = threadIdx.x >> 6;
    const int l15 = lane & 15, g = lane >> 4;
    const int qg = wave >> 1, s = wave & 1;
    const int q0 = qtile * 128 + qg * 32;
    const float maskf = (float)maskp[0];

    const f16* qpb = qp + (size_t)batch * 4096 * 64;
    const f16* kpb = kp + (size_t)batch * 4096 * 64;
    const f16* vpb = vpT + (size_t)batch * 64 * 4096;

    __shared__ __align__(16) char smem[8 * 4608];          // per-wave P: [32][72] f16
    f16* Pw = (f16*)(smem + wave * 4608);

    // hoist Q fragments (reused across all key chunks)
    f16x8 qf_[2][2];
#pragma unroll
    for (int qf = 0; qf < 2; ++qf)
#pragma unroll
        for (int ec = 0; ec < 2; ++ec)
            qf_[qf][ec] = *(const f16x8*)(qpb + (size_t)(q0 + qf * 16 + l15) * 64 + ec * 32 + g * 8);

    f32x4 oacc[4][2];
#pragma unroll
    for (int df = 0; df < 4; ++df)
#pragma unroll
        for (int qf = 0; qf < 2; ++qf) oacc[df][qf] = (f32x4){0.f, 0.f, 0.f, 0.f};
    float mt[2] = {NEG_INF, NEG_INF};
    float lsum[2] = {0.f, 0.f};

    for (int it = 0; it < 32; ++it) {
        const int key0 = (it * 2 + s) << 6;                // 64-key chunk, split by parity

        // ---- QK^T (swapped) ----
        f32x4 sacc[4][2];
#pragma unroll
        for (int kf = 0; kf < 4; ++kf)
#pragma unroll
            for (int qf = 0; qf < 2; ++qf) sacc[kf][qf] = (f32x4){0.f, 0.f, 0.f, 0.f};
#pragma unroll
        for (int ec = 0; ec < 2; ++ec) {
#pragma unroll
            for (int kf = 0; kf < 4; ++kf) {
                f16x8 ka = *(const f16x8*)(kpb + (size_t)(key0 + kf * 16 + l15) * 64 + ec * 32 + g * 8);
#pragma unroll
                for (int qf = 0; qf < 2; ++qf)
                    sacc[kf][qf] = mfma16(ka, qf_[qf][ec], sacc[kf][qf]);
            }
        }

        // ---- online softmax (per q-fragment) ----
#pragma unroll
        for (int qf = 0; qf < 2; ++qf) {
            float pm = NEG_INF;
#pragma unroll
            for (int kf = 0; kf < 4; ++kf)
#pragma unroll
                for (int r = 0; r < 4; ++r) {
                    float sc = sacc[kf][qf][r] * 0.125f;        // / sqrt(64)
                    float t = (sc == maskf) ? NEG_INF : sc * L2E;
                    sacc[kf][qf][r] = t;
                    pm = fmaxf(pm, t);
                }
            pm = fmaxf(pm, __shfl_xor(pm, 16));
            pm = fmaxf(pm, __shfl_xor(pm, 32));
            float mnew = fmaxf(mt[qf], pm);
            float alpha = __builtin_amdgcn_exp2f(mt[qf] - mnew);
            mt[qf] = mnew;
            float ps = 0.f;
#pragma unroll
            for (int kf = 0; kf < 4; ++kf) {
                f16x4 pk;
#pragma unroll
                for (int r = 0; r < 4; ++r) {
                    float pv = __builtin_amdgcn_exp2f(sacc[kf][qf][r] - mnew);
                    ps += pv;
                    pk[r] = (f16)pv;
                }
                // P[q][key]: keys kf*16 + g*4 + r  (4 consecutive -> b64)
                *(f16x4*)(&Pw[(qf * 16 + l15) * 72 + kf * 16 + g * 4]) = pk;
            }
            ps += __shfl_xor(ps, 16);
            ps += __shfl_xor(ps, 32);
            lsum[qf] = lsum[qf] * alpha + ps;
#pragma unroll
            for (int df = 0; df < 4; ++df)
#pragma unroll
                for (int r = 0; r < 4; ++r) oacc[df][qf][r] *= alpha;
        }

        // ---- PV ----
#pragma unroll
        for (int kc = 0; kc < 2; ++kc) {
            f16x8 pb[2];
#pragma unroll
            for (int qf = 0; qf < 2; ++qf)
                pb[qf] = *(const f16x8*)(&Pw[(qf * 16 + l15) * 72 + kc * 32 + g * 8]);
#pragma unroll
            for (int df = 0; df < 4; ++df) {
                f16x8 va = *(const f16x8*)(vpb + (size_t)(df * 16 + l15) * 4096 + key0 + kc * 32 + g * 8);
#pragma unroll
                for (int qf = 0; qf < 2; ++qf)
                    oacc[df][qf] = mfma16(va, pb[qf], oacc[df][qf]);
            }
        }
    }

    // ---- combine the two key-split waves of each pair ----
    __syncthreads();
    float* cO = (float*)smem + (size_t)qg * 2112;   // 2048 O + 64 m/l per pair
    if (s == 1) {
#pragma unroll
        for (int df = 0; df < 4; ++df)
#pragma unroll
            for (int qf = 0; qf < 2; ++qf)
#pragma unroll
                for (int r = 0; r < 4; ++r)
                    cO[(df * 16 + g * 4 + r) * 32 + qf * 16 + l15] = oacc[df][qf][r];
        if (lane < 16) {
#pragma unroll
            for (int qf = 0; qf < 2; ++qf) {
                cO[2048 + qf * 16 + lane] = mt[qf];
                cO[2048 + 32 + qf * 16 + lane] = lsum[qf];
            }
        }
    }
    __syncthreads();
    if (s == 0) {
        float* o0 = out + ((size_t)batch * 4096 + q0) * 64;
#pragma unroll
        for (int qf = 0; qf < 2; ++qf) {
            float mB = cO[2048 + qf * 16 + l15];
            float lB = cO[2048 + 32 + qf * 16 + l15];
            float mst = fmaxf(mt[qf], mB);
            float fA = __builtin_amdgcn_exp2f(mt[qf] - mst);
            float fB = __builtin_amdgcn_exp2f(mB - mst);
            float inv = 1.0f / (lsum[qf] * fA + lB * fB);
#pragma unroll
            for (int df = 0; df < 4; ++df) {
                float4 v;
                v.x = (oacc[df][qf][0] * fA + cO[(df * 16 + g * 4 + 0) * 32 + qf * 16 + l15] * fB) * inv;
                v.y = (oacc[df][qf][1] * fA + cO[(df * 16 + g * 4 + 1) * 32 + qf * 16 + l15] * fB) * inv;
                v.z = (oacc[df][qf][2] * fA + cO[(df * 16 + g * 4 + 2) * 32 + qf * 16 + l15] * fB) * inv;
                v.w = (oacc[df][qf][3] * fA + cO[(df * 16 + g * 4 + 3) * 32 + qf * 16 + l15] * fB) * inv;
                *(float4*)(o0 + (size_t)(qf * 16 + l15) * 64 + df * 16 + g * 4) = v;
            }
        }
    }
}

// ---------------------------------------------------------------------------
extern "C" void kernel_launch(void* const* d_in, const int* in_sizes, int n_in,
                              void* d_out, int out_size, void* d_ws, size_t ws_size,
                              hipStream_t stream) {
    const float* q  = (const float*)d_in[0];
    const float* k  = (const float*)d_in[1];
    const float* v  = (const float*)d_in[2];
    const float* Wq = (const float*)d_in[3];
    const float* bq = (const float*)d_in[4];
    const float* Wk = (const float*)d_in[5];
    const float* bk = (const float*)d_in[6];
    const float* Wv = (const float*)d_in[7];
    const float* bv = (const float*)d_in[8];
    const int* mask = (const int*)d_in[9];
    float* out = (float*)d_out;

    const size_t NTOK = (size_t)8 * 4096;      // 32768 rows
    f16* qp  = (f16*)d_ws;                     // [8][4096][64]
    f16* kp  = qp + NTOK * 64;                 // [8][4096][64]
    f16* vpT = kp + NTOK * 64;                 // [8][64][4096]
    f16* WT  = vpT + NTOK * 64;                // [3][64][512]

    ah_wt_prep<<<dim3(3), 256, 0, stream>>>(Wq, Wk, Wv, WT);
    ah_proj<<<dim3(256, 3), 256, 0, stream>>>(q, k, v, bq, bk, bv, WT, qp, kp, vpT);
    ah_attn<<<dim3(256), 512, 0, stream>>>(qp, kp, vpT, mask, out);
}

// Round 3
// 193.458 us; speedup vs baseline: 1.1860x; 1.1860x over previous
//
#include <hip/hip_runtime.h>

typedef _Float16 f16;
typedef _Float16 f16x2 __attribute__((ext_vector_type(2)));
typedef _Float16 f16x4 __attribute__((ext_vector_type(4)));
typedef _Float16 f16x8 __attribute__((ext_vector_type(8)));
typedef __fp16   h16x2 __attribute__((ext_vector_type(2)));
typedef float    f32x4 __attribute__((ext_vector_type(4)));

#define NEG_INF (-__builtin_inff())
static constexpr float L2E = 1.44269504088896340736f;

static __device__ __forceinline__ f32x4 mfma16(f16x8 a, f16x8 b, f32x4 c) {
    return __builtin_amdgcn_mfma_f32_16x16x32_f16(a, b, c, 0, 0, 0);
}

static __device__ __forceinline__ f16x2 cvt_pk(float a, float b) {
    h16x2 t = __builtin_amdgcn_cvt_pkrtz(a, b);
    return __builtin_bit_cast(f16x2, t);
}

// ---------------------------------------------------------------------------
// Kernel 0: transpose W [512][64] f32 -> WT [64][512] f16 (per tensor)
// ---------------------------------------------------------------------------
__global__ void ah_wt_prep(const float* __restrict__ Wq,
                           const float* __restrict__ Wk,
                           const float* __restrict__ Wv,
                           f16* __restrict__ WT) {
    const float* W = (blockIdx.x == 0) ? Wq : (blockIdx.x == 1) ? Wk : Wv;
    f16* o = WT + (size_t)blockIdx.x * (64 * 512);
    for (int i = threadIdx.x; i < 64 * 512; i += blockDim.x) {
        int col = i >> 9, e = i & 511;
        o[i] = (f16)W[e * 64 + col];
    }
}

// ---------------------------------------------------------------------------
// Kernel 1: projection  P = X @ W + b   (X fp32 [32768][512], out f16)
// grid (256 row-tiles, 3 tensors), block 256 (4 waves x 32 rows)
// tensor 0 -> qp row-major, 1 -> kp row-major, 2 -> vpT transposed [b][64][4096]
// ---------------------------------------------------------------------------
__global__ __launch_bounds__(256) void ah_proj(
    const float* __restrict__ Xq, const float* __restrict__ Xk, const float* __restrict__ Xv,
    const float* __restrict__ bq, const float* __restrict__ bk, const float* __restrict__ bv,
    const f16* __restrict__ WT,
    f16* __restrict__ qp, f16* __restrict__ kp, f16* __restrict__ vpT) {

    const int tens = blockIdx.y;
    const float* X    = (tens == 0) ? Xq : (tens == 1) ? Xk : Xv;
    const float* bias = (tens == 0) ? bq : (tens == 1) ? bk : bv;
    const f16* wt = WT + (size_t)tens * (64 * 512);

    const int lane = threadIdx.x & 63;
    const int wave = threadIdx.x >> 6;
    const int l15 = lane & 15, g = lane >> 4;
    const int row0 = blockIdx.x * 128;   // global row base of this block
    const int wrow = wave * 32;          // row base within block

    f32x4 acc[2][4];
#pragma unroll
    for (int a = 0; a < 2; ++a)
#pragma unroll
        for (int b = 0; b < 4; ++b) acc[a][b] = (f32x4){0.f, 0.f, 0.f, 0.f};

#pragma unroll 4
    for (int ec = 0; ec < 16; ++ec) {            // K = 512 in chunks of 32
        f16x8 af[2];
#pragma unroll
        for (int rf = 0; rf < 2; ++rf) {
            const float* px = X + (size_t)(row0 + wrow + rf * 16 + l15) * 512 + ec * 32 + g * 8;
            float4 v0 = *(const float4*)px;
            float4 v1 = *(const float4*)(px + 4);
            f16x2 p0 = cvt_pk(v0.x, v0.y);
            f16x2 p1 = cvt_pk(v0.z, v0.w);
            f16x2 p2 = cvt_pk(v1.x, v1.y);
            f16x2 p3 = cvt_pk(v1.z, v1.w);
            f16x8 a;
            a[0] = p0[0]; a[1] = p0[1]; a[2] = p1[0]; a[3] = p1[1];
            a[4] = p2[0]; a[5] = p2[1]; a[6] = p3[0]; a[7] = p3[1];
            af[rf] = a;
        }
#pragma unroll
        for (int cf = 0; cf < 4; ++cf) {
            f16x8 bfr = *(const f16x8*)(wt + (size_t)(cf * 16 + l15) * 512 + ec * 32 + g * 8);
#pragma unroll
            for (int rf = 0; rf < 2; ++rf)
                acc[rf][cf] = mfma16(af[rf], bfr, acc[rf][cf]);
        }
    }

    // epilogue: bias + f16, stage in LDS [128][68]
    __shared__ __align__(16) f16 lds[128 * 68];
#pragma unroll
    for (int rf = 0; rf < 2; ++rf)
#pragma unroll
        for (int cf = 0; cf < 4; ++cf) {
            float b = bias[cf * 16 + l15];
#pragma unroll
            for (int r = 0; r < 4; ++r) {
                int rr = wrow + rf * 16 + g * 4 + r;   // C layout: row=(l>>4)*4+r
                lds[rr * 68 + cf * 16 + l15] = (f16)(acc[rf][cf][r] + b);
            }
        }
    __syncthreads();

    if (tens < 2) {
        f16* o = ((tens == 0) ? qp : kp) + (size_t)row0 * 64;
        for (int c = threadIdx.x; c < 128 * 16; c += 256) {  // 8B chunks
            int r = c >> 4, ch = c & 15;
            *(f16x4*)(o + r * 64 + ch * 4) = *(const f16x4*)(&lds[r * 68 + ch * 4]);
        }
    } else {
        int b = row0 >> 12, n0 = row0 & 4095;
        f16* o = vpT + (size_t)b * 64 * 4096 + n0;
        for (int c = threadIdx.x; c < 64 * 32; c += 256) {   // 64 dvals x 32 chunks of 4 n
            int d = c >> 5, nch = c & 31;
            f16x4 v;
#pragma unroll
            for (int j = 0; j < 4; ++j) v[j] = lds[(nch * 4 + j) * 68 + d];
            *(f16x4*)(o + (size_t)d * 4096 + nch * 4) = v;
        }
    }
}

// ---------------------------------------------------------------------------
// Kernel 2: fused flash attention.
// grid 512: batch = id&7 (XCD-pinned K/V in L2), qtile = id>>3 (64 q-rows).
// block 512 = 8 waves: qgroup = w>>2 (32 q each), keysplit s = w&3.
// Each wave: 32 q x 1024 keys (16 chunks of 64, strided by s).
// Swapped QK^T: S^T[key][q] = mfma(A=kp, B=qp). Online softmax, exp2 domain.
// PV: O^T[dval][q] = mfma(A=vpT, B=P^T) with P via wave-private LDS.
// Epilogue: 4-way tree combine per qgroup in recycled P LDS (lane-linear).
// ---------------------------------------------------------------------------
__global__ __launch_bounds__(512, 4) void ah_attn(
    const f16* __restrict__ qp, const f16* __restrict__ kp, const f16* __restrict__ vpT,
    const int* __restrict__ maskp, float* __restrict__ out) {

    const int id = blockIdx.x;
    const int batch = id & 7, qtile = id >> 3;
    const int lane = threadIdx.x & 63, wave = threadIdx.x >> 6;
    const int l15 = lane & 15, g = lane >> 4;
    const int qg = wave >> 2, s = wave & 3;
    const int q0 = qtile * 64 + qg * 32;
    const float maskf = (float)maskp[0];

    const f16* qpb = qp + (size_t)batch * 4096 * 64;
    const f16* kpb = kp + (size_t)batch * 4096 * 64;
    const f16* vpb = vpT + (size_t)batch * 64 * 4096;

    __shared__ __align__(16) char smem[8 * 4608];   // per-wave P: [32][72] f16; recycled for combine
    __shared__ float mlx[2][2][4][32];              // [m|l][qg][s][q]
    f16* Pw = (f16*)(smem + wave * 4608);

    // hoist Q fragments (reused across all key chunks)
    f16x8 qf_[2][2];
#pragma unroll
    for (int qf = 0; qf < 2; ++qf)
#pragma unroll
        for (int ec = 0; ec < 2; ++ec)
            qf_[qf][ec] = *(const f16x8*)(qpb + (size_t)(q0 + qf * 16 + l15) * 64 + ec * 32 + g * 8);

    f32x4 oacc[4][2];
#pragma unroll
    for (int df = 0; df < 4; ++df)
#pragma unroll
        for (int qf = 0; qf < 2; ++qf) oacc[df][qf] = (f32x4){0.f, 0.f, 0.f, 0.f};
    float mt[2] = {NEG_INF, NEG_INF};
    float lsum[2] = {0.f, 0.f};

    for (int it = 0; it < 16; ++it) {
        const int key0 = (it * 4 + s) << 6;         // 64-key chunk, 4-way split

        // ---- QK^T (swapped) ----
        f32x4 sacc[4][2];
#pragma unroll
        for (int kf = 0; kf < 4; ++kf)
#pragma unroll
            for (int qf = 0; qf < 2; ++qf) sacc[kf][qf] = (f32x4){0.f, 0.f, 0.f, 0.f};
#pragma unroll
        for (int ec = 0; ec < 2; ++ec) {
#pragma unroll
            for (int kf = 0; kf < 4; ++kf) {
                f16x8 ka = *(const f16x8*)(kpb + (size_t)(key0 + kf * 16 + l15) * 64 + ec * 32 + g * 8);
#pragma unroll
                for (int qf = 0; qf < 2; ++qf)
                    sacc[kf][qf] = mfma16(ka, qf_[qf][ec], sacc[kf][qf]);
            }
        }

        // ---- online softmax (per q-fragment) ----
#pragma unroll
        for (int qf = 0; qf < 2; ++qf) {
            float pm = NEG_INF;
#pragma unroll
            for (int kf = 0; kf < 4; ++kf)
#pragma unroll
                for (int r = 0; r < 4; ++r) {
                    float sc = sacc[kf][qf][r] * 0.125f;        // / sqrt(64)
                    float t = (sc == maskf) ? NEG_INF : sc * L2E;
                    sacc[kf][qf][r] = t;
                    pm = fmaxf(pm, t);
                }
            pm = fmaxf(pm, __shfl_xor(pm, 16));
            pm = fmaxf(pm, __shfl_xor(pm, 32));
            float mnew = fmaxf(mt[qf], pm);
            float alpha = __builtin_amdgcn_exp2f(mt[qf] - mnew);
            mt[qf] = mnew;
            float ps = 0.f;
#pragma unroll
            for (int kf = 0; kf < 4; ++kf) {
                f16x4 pk;
#pragma unroll
                for (int r = 0; r < 4; ++r) {
                    float pv = __builtin_amdgcn_exp2f(sacc[kf][qf][r] - mnew);
                    ps += pv;
                    pk[r] = (f16)pv;
                }
                // P[q][key]: keys kf*16 + g*4 + r  (4 consecutive -> b64)
                *(f16x4*)(&Pw[(qf * 16 + l15) * 72 + kf * 16 + g * 4]) = pk;
            }
            ps += __shfl_xor(ps, 16);
            ps += __shfl_xor(ps, 32);
            lsum[qf] = lsum[qf] * alpha + ps;
#pragma unroll
            for (int df = 0; df < 4; ++df)
#pragma unroll
                for (int r = 0; r < 4; ++r) oacc[df][qf][r] *= alpha;
        }

        // ---- PV ----
#pragma unroll
        for (int kc = 0; kc < 2; ++kc) {
            f16x8 pb[2];
#pragma unroll
            for (int qf = 0; qf < 2; ++qf)
                pb[qf] = *(const f16x8*)(&Pw[(qf * 16 + l15) * 72 + kc * 32 + g * 8]);
#pragma unroll
            for (int df = 0; df < 4; ++df) {
                f16x8 va = *(const f16x8*)(vpb + (size_t)(df * 16 + l15) * 4096 + key0 + kc * 32 + g * 8);
#pragma unroll
                for (int qf = 0; qf < 2; ++qf)
                    oacc[df][qf] = mfma16(va, pb[qf], oacc[df][qf]);
            }
        }
    }

    // ---- 4-way key-split combine per qgroup ----
    // exchange m/l (lanes 0..31 cover q = 0..31 of this qgroup)
    if (lane < 32) {
        mlx[0][qg][s][lane] = mt[lane >> 4];
        mlx[1][qg][s][lane] = lsum[lane >> 4];
    }
    __syncthreads();     // m/l visible; all waves done with their P region

    float Lv[2];
#pragma unroll
    for (int qf = 0; qf < 2; ++qf) {
        int qi = qf * 16 + l15;
        float m0 = mlx[0][qg][0][qi], m1 = mlx[0][qg][1][qi];
        float m2 = mlx[0][qg][2][qi], m3 = mlx[0][qg][3][qi];
        float M = fmaxf(fmaxf(m0, m1), fmaxf(m2, m3));
        Lv[qf] = mlx[1][qg][0][qi] * __builtin_amdgcn_exp2f(m0 - M)
               + mlx[1][qg][1][qi] * __builtin_amdgcn_exp2f(m1 - M)
               + mlx[1][qg][2][qi] * __builtin_amdgcn_exp2f(m2 - M)
               + mlx[1][qg][3][qi] * __builtin_amdgcn_exp2f(m3 - M);
        float F = __builtin_amdgcn_exp2f(mt[qf] - M);
#pragma unroll
        for (int df = 0; df < 4; ++df)
#pragma unroll
            for (int r = 0; r < 4; ++r) oacc[df][qf][r] *= F;
    }

    // tree reduce over s in recycled P region: buf[qg][j] = 2048 floats, lane-linear
    float* bufs = (float*)smem;
    if (s >= 2) {
        float* b = bufs + (size_t)(qg * 2 + (s - 2)) * 2048;
#pragma unroll
        for (int df = 0; df < 4; ++df)
#pragma unroll
            for (int qf = 0; qf < 2; ++qf)
#pragma unroll
                for (int r = 0; r < 4; ++r)
                    b[((df * 2 + qf) * 4 + r) * 64 + lane] = oacc[df][qf][r];
    }
    __syncthreads();
    if (s < 2) {
        float* b = bufs + (size_t)(qg * 2 + s) * 2048;
#pragma unroll
        for (int df = 0; df < 4; ++df)
#pragma unroll
            for (int qf = 0; qf < 2; ++qf)
#pragma unroll
                for (int r = 0; r < 4; ++r)
                    oacc[df][qf][r] += b[((df * 2 + qf) * 4 + r) * 64 + lane];
        if (s == 1) {
            float* b1 = bufs + (size_t)(qg * 2 + 1) * 2048;
#pragma unroll
            for (int df = 0; df < 4; ++df)
#pragma unroll
                for (int qf = 0; qf < 2; ++qf)
#pragma unroll
                    for (int r = 0; r < 4; ++r)
                        b1[((df * 2 + qf) * 4 + r) * 64 + lane] = oacc[df][qf][r];
        }
    }
    __syncthreads();
    if (s == 0) {
        float* b1 = bufs + (size_t)(qg * 2 + 1) * 2048;
        float* o0 = out + ((size_t)batch * 4096 + q0) * 64;
#pragma unroll
        for (int qf = 0; qf < 2; ++qf) {
            float inv = 1.0f / Lv[qf];
#pragma unroll
            for (int df = 0; df < 4; ++df) {
                float4 v;
                v.x = (oacc[df][qf][0] + b1[((df * 2 + qf) * 4 + 0) * 64 + lane]) * inv;
                v.y = (oacc[df][qf][1] + b1[((df * 2 + qf) * 4 + 1) * 64 + lane]) * inv;
                v.z = (oacc[df][qf][2] + b1[((df * 2 + qf) * 4 + 2) * 64 + lane]) * inv;
                v.w = (oacc[df][qf][3] + b1[((df * 2 + qf) * 4 + 3) * 64 + lane]) * inv;
                *(float4*)(o0 + (size_t)(qf * 16 + l15) * 64 + df * 16 + g * 4) = v;
            }
        }
    }
}

// ---------------------------------------------------------------------------
extern "C" void kernel_launch(void* const* d_in, const int* in_sizes, int n_in,
                              void* d_out, int out_size, void* d_ws, size_t ws_size,
                              hipStream_t stream) {
    const float* q  = (const float*)d_in[0];
    const float* k  = (const float*)d_in[1];
    const float* v  = (const float*)d_in[2];
    const float* Wq = (const float*)d_in[3];
    const float* bq = (const float*)d_in[4];
    const float* Wk = (const float*)d_in[5];
    const float* bk = (const float*)d_in[6];
    const float* Wv = (const float*)d_in[7];
    const float* bv = (const float*)d_in[8];
    const int* mask = (const int*)d_in[9];
    float* out = (float*)d_out;

    const size_t NTOK = (size_t)8 * 4096;      // 32768 rows
    f16* qp  = (f16*)d_ws;                     // [8][4096][64]
    f16* kp  = qp + NTOK * 64;                 // [8][4096][64]
    f16* vpT = kp + NTOK * 64;                 // [8][64][4096]
    f16* WT  = vpT + NTOK * 64;                // [3][64][512]

    ah_wt_prep<<<dim3(3), 256, 0, stream>>>(Wq, Wk, Wv, WT);
    ah_proj<<<dim3(256, 3), 256, 0, stream>>>(q, k, v, bq, bk, bv, WT, qp, kp, vpT);
    ah_attn<<<dim3(512), 512, 0, stream>>>(qp, kp, vpT, mask, out);
}